// Round 23
// baseline (31.582 us; speedup 1.0000x reference)
//
#include <hip/hip_runtime.h>

// MLP 30->24->19->14->10->6->2->1 via MFMA (v_mfma_f32_32x32x16_f16).
// R23 vs R22 (31.3us): same structure, but the per-lane x loads are 4x
// float4 instead of 8x float2 (same 64B/lane, HALF the VMEM instructions
// -> ~half the TA (instr,line) address-processing, which the R22 model
// says is the dominant residual (~17us) over the 20.6us HBM floor).
// Per-lane addressing (base = row*30 floats):
//  block0: f4 @ base+8hb, f4 @ base+8hb+4            (k = 8hb .. 8hb+7)
//  block1: f4 @ base+16+8hb                          (k = 16+8hb .. +3)
//          f4 @ base+20+6hb  (hb=0: floats 20-23; hb=1: floats 26-29,
//                             only .z,.w used for k28,29 -> no row overrun)
// Layouts (numerically verified R19-R22, absmax 1.95e-3):
//  C/D: col=lane&31, row=(reg&3)+8*(reg>>2)+4*(lane>>5).
//  A/B: lane holds elem[m_or_n=lane&31][k=16*ks+8*(lane>>5)+j].
//  Bias folded as extra K-slot (W_eff[m][FIN]=bias, act k=FIN = 1.0).

#define NTHREADS 256
#define TPW 8                  // tiles (32 rows) per wave

typedef __fp16       h2     __attribute__((ext_vector_type(2)));
typedef __fp16       half8  __attribute__((ext_vector_type(8)));
typedef float        f32x16 __attribute__((ext_vector_type(16)));
typedef unsigned int uint4v __attribute__((ext_vector_type(4)));

__device__ __forceinline__ h2 cpk(float a, float b) {
    return __builtin_bit_cast(h2, __builtin_amdgcn_cvt_pkrtz(a, b));
}
__device__ __forceinline__ h2 relu2(h2 v) {
    h2 z = {(__fp16)0.f, (__fp16)0.f};
#if __has_builtin(__builtin_elementwise_max)
    return __builtin_elementwise_max(v, z);
#else
    v.x = v.x > (__fp16)0.f ? v.x : (__fp16)0.f;
    v.y = v.y > (__fp16)0.f ? v.y : (__fp16)0.f;
    return v;
#endif
}
__device__ __forceinline__ unsigned ucast(h2 v) { return __builtin_bit_cast(unsigned, v); }

__device__ __forceinline__ f32x16 mfma_(half8 A, half8 B, f32x16 C) {
    return __builtin_amdgcn_mfma_f32_32x32x16_f16(A, B, C, 0, 0, 0);
}

// unaligned-tolerant float4 load (rows alternate 16B/8B alignment; dwordx4
// only needs dword alignment on gfx950)
__device__ __forceinline__ float4 ldg4(const float* p) {
    float4 v;
    __builtin_memcpy(&v, p, 16);
    return v;
}

// ---- weight staging: W_eff[m][k] f16, m padded to 32, k padded to KPAD ----
template <int FIN, int FOUT, int KPAD>
__device__ __forceinline__ void stageW(const float* __restrict__ W, const float* __restrict__ B,
                                       __fp16* __restrict__ sbase, int t) {
    for (int idx = t; idx < 32 * KPAD; idx += NTHREADS) {
        int m = idx / KPAD;
        int k = idx & (KPAD - 1);
        float v = 0.f;
        if (m < FOUT) {
            if (k < FIN) v = W[m * FIN + k];
            else if (k == FIN) v = B[m];
        }
        int byte = idx * 2;
        byte ^= (m & 7) << 4;
        *(__fp16*)((char*)sbase + byte) = (__fp16)v;
    }
}

// A-fragment read: lane holds W_eff[m=lane&31][k = ks*16 + 8*(lane>>5) + j]
__device__ __forceinline__ half8 ldA(const __fp16* base, int KPAD, int ks, int lane) {
    int m = lane & 31;
    int byte = (m * KPAD + ks * 16 + ((lane >> 5) & 1) * 8) * 2;
    byte ^= (m & 7) << 4;
    return __builtin_bit_cast(half8, *(const uint4v*)((const char*)base + byte));
}

// B-fragment from accumulator D, k-block regs R (0 or 8); POS = bias slot.
template <int R, int POS>
__device__ __forceinline__ half8 bfrag(const f32x16& d, int lane) {
    unsigned u0 = ucast(relu2(cpk(d[R + 0], d[R + 1])));
    unsigned u1 = ucast(relu2(cpk(d[R + 2], d[R + 3])));
    unsigned u2 = ucast(relu2(cpk(d[R + 4], d[R + 5])));
    unsigned u3 = ucast(relu2(cpk(d[R + 6], d[R + 7])));
    bool lo = (lane & 32) == 0;
    unsigned s0 = __shfl_xor(u0, 32), s1 = __shfl_xor(u1, 32);
    unsigned s2 = __shfl_xor(u2, 32), s3 = __shfl_xor(u3, 32);
    unsigned w0 = lo ? u0 : s2;
    unsigned w1 = lo ? u1 : s3;
    unsigned w2 = lo ? s0 : u2;
    unsigned w3 = lo ? s1 : u3;
    if constexpr (POS >= 0) {
        constexpr bool hiT = POS >= 8;
        constexpr int  p   = POS & 7;
        constexpr unsigned bits = (p & 1) ? 0x3C000000u : 0x00003C00u;  // f16 1.0
        bool sel = (((lane & 32) != 0) == hiT);
        unsigned ob = sel ? bits : 0u;
        if constexpr ((p >> 1) == 0) w0 |= ob;
        else if constexpr ((p >> 1) == 1) w1 |= ob;
        else if constexpr ((p >> 1) == 2) w2 |= ob;
        else w3 |= ob;
    }
    uint4v u = {w0, w1, w2, w3};
    return __builtin_bit_cast(half8, u);
}

__device__ __forceinline__ half8 packx(unsigned a, unsigned b, unsigned c, unsigned d) {
    uint4v u = {a, b, c, d};
    return __builtin_bit_cast(half8, u);
}

__global__ __launch_bounds__(NTHREADS, 4) void mlp_mfma5(
    const float* __restrict__ x,
    const float* __restrict__ W1, const float* __restrict__ B1,
    const float* __restrict__ W2, const float* __restrict__ B2,
    const float* __restrict__ W3, const float* __restrict__ B3,
    const float* __restrict__ W4, const float* __restrict__ B4,
    const float* __restrict__ W5, const float* __restrict__ B5,
    const float* __restrict__ W6, const float* __restrict__ B6,
    const float* __restrict__ W7, const float* __restrict__ B7,
    float* __restrict__ out, int nrows)
{
    __shared__ __align__(16) __fp16 shw[5120];        // weights only, 10.2 KB

    const int t    = threadIdx.x;
    const int lane = t & 63;
    const int wid  = t >> 6;
    const int hb   = (lane >> 5) & 1;

    stageW<30, 24, 32>(W1, B1, shw + 0,    t);
    stageW<24, 19, 32>(W2, B2, shw + 1024, t);
    stageW<19, 14, 32>(W3, B3, shw + 2048, t);
    stageW<14, 10, 16>(W4, B4, shw + 3072, t);
    stageW<10, 6,  16>(W5, B5, shw + 3584, t);
    stageW<6,  2,  16>(W6, B6, shw + 4096, t);
    stageW<2,  1,  16>(W7, B7, shw + 4608, t);
    __syncthreads();                                  // the ONLY barrier

    // ---- hoist all A-fragments into registers (10 x 4 VGPR) ----
    const half8 A10 = ldA(shw + 0,    32, 0, lane), A11 = ldA(shw + 0,    32, 1, lane);
    const half8 A20 = ldA(shw + 1024, 32, 0, lane), A21 = ldA(shw + 1024, 32, 1, lane);
    const half8 A30 = ldA(shw + 2048, 32, 0, lane), A31 = ldA(shw + 2048, 32, 1, lane);
    const half8 A4  = ldA(shw + 3072, 16, 0, lane);
    const half8 A5  = ldA(shw + 3584, 16, 0, lane);
    const half8 A6  = ldA(shw + 4096, 16, 0, lane);
    const half8 A7  = ldA(shw + 4608, 16, 0, lane);

    const f32x16 z = {0.f,0.f,0.f,0.f, 0.f,0.f,0.f,0.f, 0.f,0.f,0.f,0.f, 0.f,0.f,0.f,0.f};

    const int tile0 = (blockIdx.x * 4 + wid) * TPW;   // TPW consecutive tiles/wave
    const int myrow = lane & 31;
    const int off0  = hb * 8;            // block0 k-slice start
    const int off1  = 16 + hb * 8;       // block1 k-slice start
    const int off3  = 20 + hb * 6;       // last f4: 20..23 (lo) / 26..29 (hi)

    // prefetch tile 0
    float4 q0, q1, q2, q3;
    {
        const float* b = x + ((size_t)(tile0 * 32 + myrow)) * 30;
        q0 = ldg4(b + off0);
        q1 = ldg4(b + off0 + 4);
        q2 = ldg4(b + off1);
        q3 = ldg4(b + off3);
    }

    for (int it = 0; it < TPW; ++it) {
        const int T = tile0 + it;

        // ---- build layer-1 B-fragments from prefetch regs ----
        half8 Bx0 = packx(ucast(cpk(q0.x, q0.y)), ucast(cpk(q0.z, q0.w)),
                          ucast(cpk(q1.x, q1.y)), ucast(cpk(q1.z, q1.w)));
        unsigned w2 = hb ? ucast(cpk(q3.z, q3.w))    // k28,29
                         : ucast(cpk(q3.x, q3.y));   // k20,21
        unsigned w3 = hb ? 0x00003C00u               // k30=1.0 (bias), k31=0
                         : ucast(cpk(q3.z, q3.w));   // k22,23
        half8 Bx1 = packx(ucast(cpk(q2.x, q2.y)), ucast(cpk(q2.z, q2.w)), w2, w3);

        // ---- issue next tile's loads (hide under MFMA chain) ----
        if (it + 1 < TPW) {
            const float* b = x + ((size_t)((T + 1) * 32 + myrow)) * 30;
            q0 = ldg4(b + off0);
            q1 = ldg4(b + off0 + 4);
            q2 = ldg4(b + off1);
            q3 = ldg4(b + off3);
        }

        // ---- 10-MFMA chain ----
        f32x16 a1 = mfma_(A10, Bx0, z);
        a1 = mfma_(A11, Bx1, a1);
        f32x16 a2 = mfma_(A20, bfrag<0, -1>(a1, lane), z);
        a2 = mfma_(A21, bfrag<8, 8>(a1, lane), a2);
        f32x16 a3 = mfma_(A30, bfrag<0, -1>(a2, lane), z);
        a3 = mfma_(A31, bfrag<8, 3>(a2, lane), a3);
        f32x16 a4 = mfma_(A4, bfrag<0, 14>(a3, lane), z);
        f32x16 a5 = mfma_(A5, bfrag<0, 10>(a4, lane), z);
        f32x16 a6 = mfma_(A6, bfrag<0, 6>(a5, lane), z);
        f32x16 a7 = mfma_(A7, bfrag<0, 2>(a6, lane), z);

        const int row0 = T * 32;
        if (lane < 32) {
            int r = row0 + lane;
            if (r < nrows) out[r] = a7[0];
        }
    }
}

extern "C" void kernel_launch(void* const* d_in, const int* in_sizes, int n_in,
                              void* d_out, int out_size, void* d_ws, size_t ws_size,
                              hipStream_t stream) {
    const float* x = (const float*)d_in[0];
    int nrows = in_sizes[0] / 30;
    int rows_per_block = 4 * TPW * 32;                // 1024
    int blocks = (nrows + rows_per_block - 1) / rows_per_block;
    mlp_mfma5<<<blocks, NTHREADS, 0, stream>>>(
        x,
        (const float*)d_in[1],  (const float*)d_in[2],
        (const float*)d_in[3],  (const float*)d_in[4],
        (const float*)d_in[5],  (const float*)d_in[6],
        (const float*)d_in[7],  (const float*)d_in[8],
        (const float*)d_in[9],  (const float*)d_in[10],
        (const float*)d_in[11], (const float*)d_in[12],
        (const float*)d_in[13], (const float*)d_in[14],
        (float*)d_out, nrows);
}